// Round 3
// baseline (306.183 us; speedup 1.0000x reference)
//
#include <hip/hip_runtime.h>
#include <hip/hip_bf16.h>
#include <math.h>

namespace {

constexpr int kB = 32;
constexpr int kS = 2048;
constexpr int kI = 32;
constexpr int kW = 20;
constexpr int kH = 128;
constexpr int kNwin = kS - kW + 1;   // 2029
constexpr int kT = kS - 2 * kW;      // 2008
constexpr float kEps = 1e-5f;

__device__ __forceinline__ float gelu_exact(float v) {
    return 0.5f * v * (1.0f + erff(v * 0.70710678118654752440f));
}

// ================= encoder =================
// Block: 64 t-rows, 256 threads = 4 waves. Lane owns one t-row; wave w owns
// column slice [w*32, w*32+32). A comes from LDS (1 conflict-free b32 per k),
// W is wave-uniform -> scalar loads -> v_fmac with SGPR operand.
constexpr int ETT = 64;              // t-rows per block
constexpr int XSR = ETT + kW - 1;    // 83 x-rows staged
constexpr int XST = 33;              // odd stride => (row+k)%32 banks, 2-way max

__global__ __launch_bounds__(256, 4)
void enc_kernel(const float* __restrict__ x, const float* __restrict__ Wenc,
                const float* __restrict__ benc, const float* __restrict__ gma,
                const float* __restrict__ bta, float* __restrict__ enc)
{
    __shared__ float xs[XSR * XST];      // 2739 floats (~11 KB)
    __shared__ float red[2][4][ETT];     // LN partial sums (2 KB)

    const int tid  = threadIdx.x;
    const int b    = blockIdx.y;
    const int t0   = blockIdx.x * ETT;
    const int lane = tid & 63;
    const int wv   = tid >> 6;                                   // 0..3
    const int col0 = __builtin_amdgcn_readfirstlane(wv * 32);    // uniform col base

    // stage x rows [t0, t0+83) (clamped), coalesced float4 -> 4x b32 LDS writes
    const float4* x4 = reinterpret_cast<const float4*>(x + (size_t)b * kS * kI);
    for (int i = tid; i < XSR * 8; i += 256) {
        int r = i >> 3, c4 = i & 7;
        int gr = t0 + r; if (gr > kS - 1) gr = kS - 1;
        float4 v = x4[gr * 8 + c4];
        float* dst = &xs[r * XST + c4 * 4];
        dst[0] = v.x; dst[1] = v.y; dst[2] = v.z; dst[3] = v.w;
    }
    __syncthreads();

    float acc[32];
    #pragma unroll
    for (int j = 0; j < 32; ++j) acc[j] = 0.0f;

    // K = 640: k = kc*32 + kk -> A = x[t + kc][kk]
    for (int kc = 0; kc < 20; ++kc) {
        const int abase = (lane + kc) * XST;
        #pragma unroll 4
        for (int kk = 0; kk < 32; ++kk) {
            const float a = xs[abase + kk];                       // 1 b32, 2-way max
            const float* wk = Wenc + (kc * 32 + kk) * kH + col0;  // uniform -> s_load
            #pragma unroll
            for (int j = 0; j < 32; ++j)
                acc[j] = fmaf(a, wk[j], acc[j]);
        }
    }

    // bias + LN partial sum
    float ps = 0.0f;
    #pragma unroll
    for (int j = 0; j < 32; ++j) { acc[j] += benc[col0 + j]; ps += acc[j]; }
    red[0][wv][lane] = ps;
    __syncthreads();
    const float mu = (red[0][0][lane] + red[0][1][lane] + red[0][2][lane] + red[0][3][lane])
                     * (1.0f / 128.0f);
    float vs = 0.0f;
    #pragma unroll
    for (int j = 0; j < 32; ++j) { acc[j] -= mu; vs += acc[j] * acc[j]; }
    red[1][wv][lane] = vs;
    __syncthreads();
    const float var = (red[1][0][lane] + red[1][1][lane] + red[1][2][lane] + red[1][3][lane])
                      * (1.0f / 128.0f);
    const float rstd = 1.0f / sqrtf(var + kEps);

    const int t = t0 + lane;
    if (t < kNwin) {
        float o[32];
        #pragma unroll
        for (int j = 0; j < 32; ++j)
            o[j] = gelu_exact(acc[j] * rstd * gma[col0 + j] + bta[col0 + j]);
        float4* dst = reinterpret_cast<float4*>(enc + ((size_t)(b * kS + t)) * kH + col0);
        #pragma unroll
        for (int q = 0; q < 8; ++q)
            dst[q] = make_float4(o[q * 4], o[q * 4 + 1], o[q * 4 + 2], o[q * 4 + 3]);
    }
}

// ================= comparator MLP: 256 -> 128 -> 64 -> 1 =================
// Block: 64 t-rows, 256 threads = 4 waves. Lane owns row t; waves split columns.
constexpr int CTT = 64;
constexpr int CSR = CTT + kW;        // 84 enc rows staged
constexpr int EST = 129;             // odd stride, 2-way max
constexpr int Z2ST = 65;
// pool: phase1 encb 84*129 = 10836 ; phase2 z1b 64*129 = 8256 + z2b 64*65 = 4160 -> 12416
constexpr int POOL = 12416;

__global__ __launch_bounds__(256, 3)
void cmp_kernel(const float* __restrict__ enc,
                const float* __restrict__ W1, const float* __restrict__ b1,
                const float* __restrict__ W2, const float* __restrict__ b2,
                const float* __restrict__ W3, const float* __restrict__ b3,
                float* __restrict__ out)
{
    __shared__ float pool[POOL];     // 49.7 KB
    const int tid  = threadIdx.x;
    const int b    = blockIdx.y;
    const int t0   = blockIdx.x * CTT;
    const int lane = tid & 63;
    const int wv   = tid >> 6;

    float* encb = pool;              // 84 x 129 (phase 1)
    float* z1b  = pool;              // 64 x 129 (phase 2, overlays encb after barrier)
    float* z2b  = pool + 8256;       // 64 x 65  (phase 2)

    // stage enc rows [t0, t0+84) (clamped to <= 2028)
    const float4* e4 = reinterpret_cast<const float4*>(enc);
    for (int i = tid; i < CSR * 32; i += 256) {
        int r = i >> 5, c4 = i & 31;
        int gr = t0 + r; if (gr > kNwin - 1) gr = kNwin - 1;
        float4 v = e4[((size_t)(b * kS + gr)) * 32 + c4];
        float* dst = &encb[r * EST + c4 * 4];
        dst[0] = v.x; dst[1] = v.y; dst[2] = v.z; dst[3] = v.w;
    }
    __syncthreads();

    // ---- layer 1: K=256 (first 128 from enc[t], next 128 from enc[t+20]) ----
    const int col0 = __builtin_amdgcn_readfirstlane(wv * 32);
    float acc1[32];
    #pragma unroll
    for (int j = 0; j < 32; ++j) acc1[j] = 0.0f;

    {
        const int abase = lane * EST;
        #pragma unroll 4
        for (int k = 0; k < 128; ++k) {
            const float a = encb[abase + k];
            const float* wk = W1 + k * kH + col0;
            #pragma unroll
            for (int j = 0; j < 32; ++j) acc1[j] = fmaf(a, wk[j], acc1[j]);
        }
    }
    {
        const int abase = (lane + kW) * EST;
        #pragma unroll 4
        for (int k = 0; k < 128; ++k) {
            const float a = encb[abase + k];
            const float* wk = W1 + (128 + k) * kH + col0;
            #pragma unroll
            for (int j = 0; j < 32; ++j) acc1[j] = fmaf(a, wk[j], acc1[j]);
        }
    }
    __syncthreads();   // done reading encb
    #pragma unroll
    for (int j = 0; j < 32; ++j)
        z1b[lane * EST + col0 + j] = gelu_exact(acc1[j] + b1[col0 + j]);
    __syncthreads();

    // ---- layer 2: K=128 -> 64 cols; wave owns 16 cols ----
    const int col2 = __builtin_amdgcn_readfirstlane(wv * 16);
    float acc2[16];
    #pragma unroll
    for (int j = 0; j < 16; ++j) acc2[j] = 0.0f;
    {
        const int abase = lane * EST;
        #pragma unroll 4
        for (int k = 0; k < 128; ++k) {
            const float a = z1b[abase + k];
            const float* wk = W2 + k * 64 + col2;
            #pragma unroll
            for (int j = 0; j < 16; ++j) acc2[j] = fmaf(a, wk[j], acc2[j]);
        }
    }
    #pragma unroll
    for (int j = 0; j < 16; ++j)
        z2b[lane * Z2ST + col2 + j] = gelu_exact(acc2[j] + b2[col2 + j]);
    __syncthreads();

    // ---- layer 3: K=64 -> 1, sigmoid; wave 0 computes & stores ----
    if (wv == 0) {
        float s = 0.0f;
        const int abase = lane * Z2ST;
        #pragma unroll
        for (int k = 0; k < 64; ++k) s = fmaf(z2b[abase + k], W3[k], s);
        const int t = t0 + lane;
        if (t < kT) {
            const float p = 1.0f / (1.0f + expf(-(s + b3[0])));
            out[(size_t)b * kS + t + kW] = p;
            out[(size_t)kB * kS + (size_t)b * kS + t + kW] = (p > 0.5f) ? 1.0f : 0.0f;
        }
    }
}

}  // namespace

extern "C" void kernel_launch(void* const* d_in, const int* in_sizes, int n_in,
                              void* d_out, int out_size, void* d_ws, size_t ws_size,
                              hipStream_t stream)
{
    const float* x    = (const float*)d_in[0];
    const float* Wenc = (const float*)d_in[1];
    const float* benc = (const float*)d_in[2];
    const float* gma  = (const float*)d_in[3];
    const float* bta  = (const float*)d_in[4];
    const float* W1   = (const float*)d_in[5];
    const float* b1   = (const float*)d_in[6];
    const float* W2   = (const float*)d_in[7];
    const float* b2   = (const float*)d_in[8];
    const float* W3   = (const float*)d_in[9];
    const float* b3   = (const float*)d_in[10];
    float* out = (float*)d_out;
    float* enc = (float*)d_ws;   // 32 * 2048 * 128 floats = 33.5 MB scratch

    hipMemsetAsync(d_out, 0, (size_t)out_size * sizeof(float), stream);

    // 32*64 = 2048 t-rows per batch; 1024 blocks each (4 per CU)
    enc_kernel<<<dim3(32, kB), 256, 0, stream>>>(x, Wenc, benc, gma, bta, enc);
    cmp_kernel<<<dim3(32, kB), 256, 0, stream>>>(enc, W1, b1, W2, b2, W3, b3, out);
}

// Round 4
// 265.748 us; speedup vs baseline: 1.1522x; 1.1522x over previous
//
#include <hip/hip_runtime.h>
#include <hip/hip_bf16.h>
#include <math.h>

namespace {

constexpr int kB = 32;
constexpr int kS = 2048;
constexpr int kI = 32;
constexpr int kW = 20;
constexpr int kH = 128;
constexpr int kNwin = kS - kW + 1;   // 2029
constexpr int kT = kS - 2 * kW;      // 2008
constexpr float kEps = 1e-5f;

__device__ __forceinline__ float gelu_exact(float v) {
    return 0.5f * v * (1.0f + erff(v * 0.70710678118654752440f));
}

// ============ encoder: h = win @ W_enc + b ; LN ; GELU ============
// 256 thr, tile 128t x 128H, thread-tile 4x16.
// A staged TRANSPOSED xsT[k][row] so 4 consecutive rows = one float4.
// W staged bank-swizzled: [kk][(col/16)*20 + col%16] -> 8 rc-groups hit
// 8 distinct bank quads (rc*20 % 32 = {0,20,8,28,16,4,24,12}) -> conflict-free.
constexpr int ETT = 128;
constexpr int XSR = ETT + kW - 1;     // 147 x-rows staged
constexpr int XRP = 152;              // padded row-dim (152*4B % 16 == 0)

__global__ __launch_bounds__(256, 2)
void enc_kernel(const float* __restrict__ x, const float* __restrict__ Wenc,
                const float* __restrict__ benc, const float* __restrict__ gma,
                const float* __restrict__ bta, float* __restrict__ enc)
{
    __shared__ float xsT[32 * XRP];    // 4864 f (19.5 KB), transposed
    __shared__ float wb[32 * 160];     // 5120 f (20.5 KB), swizzled

    const int tid = threadIdx.x;
    const int b   = blockIdx.y;
    const int t0  = blockIdx.x * ETT;
    const int rc  = tid & 7;          // cols rc*16 .. +15
    const int rt  = tid >> 3;         // rows rt*4 .. +3   (0..31)

    // stage xsT: thread r loads x row t0+r (128B contiguous) and scatters transposed.
    // writes: fixed kk, lanes r consecutive -> conflict-free.
    if (tid < XSR) {
        int gr = t0 + tid; if (gr > kS - 1) gr = kS - 1;
        const float4* xr = reinterpret_cast<const float4*>(x) + ((size_t)b * kS + gr) * 8;
        #pragma unroll
        for (int c4 = 0; c4 < 8; ++c4) {
            float4 v = xr[c4];
            xsT[(c4 * 4 + 0) * XRP + tid] = v.x;
            xsT[(c4 * 4 + 1) * XRP + tid] = v.y;
            xsT[(c4 * 4 + 2) * XRP + tid] = v.z;
            xsT[(c4 * 4 + 3) * XRP + tid] = v.w;
        }
    }

    float acc[4][16];
    #pragma unroll
    for (int i = 0; i < 4; ++i)
        #pragma unroll
        for (int j = 0; j < 16; ++j) acc[i][j] = 0.0f;

    const float4* W4 = reinterpret_cast<const float4*>(Wenc);

    for (int kc4 = 0; kc4 < 5; ++kc4) {
        #pragma unroll
        for (int sub = 0; sub < 4; ++sub) {
            const int kc = kc4 * 4 + sub;          // chunk: k = kc*32 + kk, A row = t + kc
            __syncthreads();
            #pragma unroll
            for (int q = 0; q < 4; ++q) {          // stage W chunk (32k x 128col), swizzled
                int i = tid + 256 * q;
                int kkr = i >> 5, c4 = i & 31;
                float4 v = W4[(size_t)(kc * 32 + kkr) * 32 + c4];
                int col = c4 << 2;
                float* dst = &wb[kkr * 160 + (col >> 4) * 20 + (col & 15)];
                dst[0] = v.x; dst[1] = v.y; dst[2] = v.z; dst[3] = v.w;
            }
            __syncthreads();
            const int arow = (rt + kc4) * 4;       // aligned base; shift by 'sub' (static)
            #pragma unroll 8
            for (int kk = 0; kk < 32; ++kk) {
                const float* xk = &xsT[kk * XRP + arow];
                const float4 lo = *reinterpret_cast<const float4*>(xk);
                float a0, a1, a2, a3;
                if (sub == 0)      { a0 = lo.x; a1 = lo.y; a2 = lo.z; a3 = lo.w; }
                else {
                    const float4 hi = *reinterpret_cast<const float4*>(xk + 4);
                    if (sub == 1)      { a0 = lo.y; a1 = lo.z; a2 = lo.w; a3 = hi.x; }
                    else if (sub == 2) { a0 = lo.z; a1 = lo.w; a2 = hi.x; a3 = hi.y; }
                    else               { a0 = lo.w; a1 = hi.x; a2 = hi.y; a3 = hi.z; }
                }
                const float a[4] = {a0, a1, a2, a3};
                const float* wr = &wb[kk * 160 + rc * 20];
                float w[16];
                *reinterpret_cast<float4*>(&w[0])  = *reinterpret_cast<const float4*>(wr);
                *reinterpret_cast<float4*>(&w[4])  = *reinterpret_cast<const float4*>(wr + 4);
                *reinterpret_cast<float4*>(&w[8])  = *reinterpret_cast<const float4*>(wr + 8);
                *reinterpret_cast<float4*>(&w[12]) = *reinterpret_cast<const float4*>(wr + 12);
                #pragma unroll
                for (int i2 = 0; i2 < 4; ++i2)
                    #pragma unroll
                    for (int j = 0; j < 16; ++j)
                        acc[i2][j] = fmaf(a[i2], w[j], acc[i2][j]);
            }
        }
    }

    // epilogue: bias + LN (reduce over the 8 rc-lanes) + GELU + store
    float bv[16], gv[16], btv[16];
    #pragma unroll
    for (int j = 0; j < 16; ++j) {
        bv[j]  = benc[rc * 16 + j];
        gv[j]  = gma[rc * 16 + j];
        btv[j] = bta[rc * 16 + j];
    }
    #pragma unroll
    for (int i = 0; i < 4; ++i) {
        const int t = t0 + rt * 4 + i;
        float h[16];
        float s = 0.0f;
        #pragma unroll
        for (int j = 0; j < 16; ++j) { h[j] = acc[i][j] + bv[j]; s += h[j]; }
        s += __shfl_xor(s, 1, 8);
        s += __shfl_xor(s, 2, 8);
        s += __shfl_xor(s, 4, 8);
        const float mu = s * (1.0f / 128.0f);
        float s2 = 0.0f;
        #pragma unroll
        for (int j = 0; j < 16; ++j) { h[j] -= mu; s2 += h[j] * h[j]; }
        s2 += __shfl_xor(s2, 1, 8);
        s2 += __shfl_xor(s2, 2, 8);
        s2 += __shfl_xor(s2, 4, 8);
        const float rstd = 1.0f / sqrtf(s2 * (1.0f / 128.0f) + kEps);
        if (t < kNwin) {
            #pragma unroll
            for (int j = 0; j < 16; ++j) h[j] = gelu_exact(h[j] * rstd * gv[j] + btv[j]);
            float4* dst = reinterpret_cast<float4*>(enc + ((size_t)(b * kS + t)) * kH + rc * 16);
            dst[0] = make_float4(h[0], h[1], h[2], h[3]);
            dst[1] = make_float4(h[4], h[5], h[6], h[7]);
            dst[2] = make_float4(h[8], h[9], h[10], h[11]);
            dst[3] = make_float4(h[12], h[13], h[14], h[15]);
        }
    }
}

// ============ comparator MLP: 256 -> 128 -> 64 -> 1, sigmoid ============
// 256 thr, tile 64t. Layer1 thread-tile 2x16, same transposed-A + swizzled-W scheme.
constexpr int CTT = 64;
constexpr int CSR = CTT + kW;   // 84 enc rows staged per chunk
constexpr int CRP = 88;         // padded row-dim
// pool layout (floats):
//   phase1: encT [32][88] = 2816 @0 ; wb1 [32][160] = 5120 @2816 (ends 7936)
//   phase2: z1 [64][132] = 8448 @0 ; w2b [32][64] = 2048 @8448 ; z2 [64][65] = 4160 @10496
constexpr int PoolF = 14656;    // 57.25 KB

__global__ __launch_bounds__(256, 2)
void cmp_kernel(const float* __restrict__ enc,
                const float* __restrict__ W1, const float* __restrict__ b1,
                const float* __restrict__ W2, const float* __restrict__ b2,
                const float* __restrict__ W3, const float* __restrict__ b3,
                float* __restrict__ out)
{
    __shared__ float pool[PoolF];
    float* encT = pool;
    float* wb1  = pool + 2816;
    float* z1   = pool;
    float* w2b  = pool + 8448;
    float* z2   = pool + 10496;

    const int tid = threadIdx.x;
    const int b   = blockIdx.y;
    const int t0  = blockIdx.x * CTT;
    const int rc  = tid & 7;          // cols rc*16 .. +15
    const int rt  = tid >> 3;         // rows rt*2 .. +1   (0..31)

    const float4* e4  = reinterpret_cast<const float4*>(enc);
    const float4* W14 = reinterpret_cast<const float4*>(W1);

    // ---- layer 1: (64 x 256) @ W1 ; A[t][k] = enc[t + (k<128?0:20)][k%128]
    float acc1[2][16];
    #pragma unroll
    for (int i = 0; i < 2; ++i)
        #pragma unroll
        for (int j = 0; j < 16; ++j) acc1[i][j] = 0.0f;

    for (int kc = 0; kc < 8; ++kc) {           // k ascending: kc*32 .. kc*32+31
        __syncthreads();
        if (tid < CSR) {                        // stage enc col-slice transposed
            int gr = t0 + tid; if (gr > kNwin - 1) gr = kNwin - 1;
            const float4* er = e4 + ((size_t)(b * kS + gr)) * 32 + (kc & 3) * 8;
            #pragma unroll
            for (int c4 = 0; c4 < 8; ++c4) {
                float4 v = er[c4];
                encT[(c4 * 4 + 0) * CRP + tid] = v.x;
                encT[(c4 * 4 + 1) * CRP + tid] = v.y;
                encT[(c4 * 4 + 2) * CRP + tid] = v.z;
                encT[(c4 * 4 + 3) * CRP + tid] = v.w;
            }
        }
        #pragma unroll
        for (int q = 0; q < 4; ++q) {           // stage W1 chunk, swizzled
            int i = tid + 256 * q;
            int kkr = i >> 5, c4 = i & 31;
            float4 v = W14[(size_t)(kc * 32 + kkr) * 32 + c4];
            int col = c4 << 2;
            float* dst = &wb1[kkr * 160 + (col >> 4) * 20 + (col & 15)];
            dst[0] = v.x; dst[1] = v.y; dst[2] = v.z; dst[3] = v.w;
        }
        __syncthreads();
        const int abase = ((kc < 4) ? 0 : kW) + rt * 2;   // even -> float2 aligned
        #pragma unroll 8
        for (int kk = 0; kk < 32; ++kk) {
            const float2 a2 = *reinterpret_cast<const float2*>(&encT[kk * CRP + abase]);
            const float a[2] = {a2.x, a2.y};
            const float* wr = &wb1[kk * 160 + rc * 20];
            float w[16];
            *reinterpret_cast<float4*>(&w[0])  = *reinterpret_cast<const float4*>(wr);
            *reinterpret_cast<float4*>(&w[4])  = *reinterpret_cast<const float4*>(wr + 4);
            *reinterpret_cast<float4*>(&w[8])  = *reinterpret_cast<const float4*>(wr + 8);
            *reinterpret_cast<float4*>(&w[12]) = *reinterpret_cast<const float4*>(wr + 12);
            #pragma unroll
            for (int i2 = 0; i2 < 2; ++i2)
                #pragma unroll
                for (int j = 0; j < 16; ++j)
                    acc1[i2][j] = fmaf(a[i2], w[j], acc1[i2][j]);
        }
    }
    __syncthreads();   // all encT/wb1 reads done
    {
        float b1v[16];
        #pragma unroll
        for (int j = 0; j < 16; ++j) b1v[j] = b1[rc * 16 + j];
        #pragma unroll
        for (int i = 0; i < 2; ++i) {
            float o[16];
            #pragma unroll
            for (int j = 0; j < 16; ++j) o[j] = gelu_exact(acc1[i][j] + b1v[j]);
            float* dst = &z1[(rt * 2 + i) * 132 + rc * 16];
            *reinterpret_cast<float4*>(dst)      = make_float4(o[0], o[1], o[2], o[3]);
            *reinterpret_cast<float4*>(dst + 4)  = make_float4(o[4], o[5], o[6], o[7]);
            *reinterpret_cast<float4*>(dst + 8)  = make_float4(o[8], o[9], o[10], o[11]);
            *reinterpret_cast<float4*>(dst + 12) = make_float4(o[12], o[13], o[14], o[15]);
        }
    }
    __syncthreads();

    // ---- layer 2: (64 x 128) @ W2(128 x 64), thread-tile 2x8 ----
    float acc2[2][8];
    #pragma unroll
    for (int i = 0; i < 2; ++i)
        #pragma unroll
        for (int j = 0; j < 8; ++j) acc2[i][j] = 0.0f;

    const float4* W24 = reinterpret_cast<const float4*>(W2);
    for (int kc2 = 0; kc2 < 4; ++kc2) {
        __syncthreads();
        #pragma unroll
        for (int q = 0; q < 2; ++q) {          // stage W2 chunk (32k x 64col)
            int idx = tid + 256 * q;
            int kkr = idx >> 4, c4 = idx & 15;
            float4 v = W24[(size_t)(kc2 * 32 + kkr) * 16 + c4];
            *reinterpret_cast<float4*>(&w2b[kkr * 64 + c4 * 4]) = v;
        }
        __syncthreads();
        #pragma unroll
        for (int kk4 = 0; kk4 < 8; ++kk4) {
            float4 a4[2];
            #pragma unroll
            for (int i = 0; i < 2; ++i)
                a4[i] = *reinterpret_cast<const float4*>(&z1[(rt * 2 + i) * 132 + kc2 * 32 + kk4 * 4]);
            #pragma unroll
            for (int u = 0; u < 4; ++u) {
                const int kkl = kk4 * 4 + u;
                const float4 w0 = *reinterpret_cast<const float4*>(&w2b[kkl * 64 + rc * 8]);
                const float4 w1v = *reinterpret_cast<const float4*>(&w2b[kkl * 64 + rc * 8 + 4]);
                const float w[8] = {w0.x, w0.y, w0.z, w0.w, w1v.x, w1v.y, w1v.z, w1v.w};
                const float av[2] = {
                    u == 0 ? a4[0].x : (u == 1 ? a4[0].y : (u == 2 ? a4[0].z : a4[0].w)),
                    u == 0 ? a4[1].x : (u == 1 ? a4[1].y : (u == 2 ? a4[1].z : a4[1].w))};
                #pragma unroll
                for (int i = 0; i < 2; ++i)
                    #pragma unroll
                    for (int j = 0; j < 8; ++j)
                        acc2[i][j] = fmaf(av[i], w[j], acc2[i][j]);
            }
        }
    }
    __syncthreads();
    {
        float b2v[8];
        #pragma unroll
        for (int j = 0; j < 8; ++j) b2v[j] = b2[rc * 8 + j];
        #pragma unroll
        for (int i = 0; i < 2; ++i)
            #pragma unroll
            for (int j = 0; j < 8; ++j)
                z2[(rt * 2 + i) * 65 + rc * 8 + j] = gelu_exact(acc2[i][j] + b2v[j]);
    }
    __syncthreads();

    // ---- layer 3: (64 x 64) @ W3 + sigmoid; stride-65 reads are conflict-free ----
    if (tid < CTT) {
        float s = 0.0f;
        #pragma unroll
        for (int k = 0; k < 64; ++k) s = fmaf(z2[tid * 65 + k], W3[k], s);
        const int t = t0 + tid;
        if (t < kT) {
            const float p = 1.0f / (1.0f + expf(-(s + b3[0])));
            out[(size_t)b * kS + t + kW] = p;
            out[(size_t)kB * kS + (size_t)b * kS + t + kW] = (p > 0.5f) ? 1.0f : 0.0f;
        }
    }
}

}  // namespace

extern "C" void kernel_launch(void* const* d_in, const int* in_sizes, int n_in,
                              void* d_out, int out_size, void* d_ws, size_t ws_size,
                              hipStream_t stream)
{
    const float* x    = (const float*)d_in[0];
    const float* Wenc = (const float*)d_in[1];
    const float* benc = (const float*)d_in[2];
    const float* gma  = (const float*)d_in[3];
    const float* bta  = (const float*)d_in[4];
    const float* W1   = (const float*)d_in[5];
    const float* b1   = (const float*)d_in[6];
    const float* W2   = (const float*)d_in[7];
    const float* b2   = (const float*)d_in[8];
    const float* W3   = (const float*)d_in[9];
    const float* b3   = (const float*)d_in[10];
    float* out = (float*)d_out;
    float* enc = (float*)d_ws;   // 32 * 2048 * 128 floats = 33.5 MB scratch

    hipMemsetAsync(d_out, 0, (size_t)out_size * sizeof(float), stream);

    // encoder: 16*128 = 2048 >= 2029 t-rows; (16,32) = 512 blocks
    enc_kernel<<<dim3(16, kB), 256, 0, stream>>>(x, Wenc, benc, gma, bta, enc);
    // comparator: 32*64 = 2048 >= 2008 t-rows; (32,32) = 1024 blocks
    cmp_kernel<<<dim3(32, kB), 256, 0, stream>>>(enc, W1, b1, W2, b2, W3, b3, out);
}